// Round 7
// baseline (25.051 us; speedup 1.0000x reference)
//
#include <hip/hip_runtime.h>
#include <math.h>

#define IMG   112
#define HW    12544
#define GRID  16
#define DP    384
#define CF    128
#define CIN   512
#define COUT  128
#define KTOP  64
#define NHEADS 6
#define NBIN  2048   // 11-bit bins of the orderable key
#define CAP   2048   // candidate capacity (expected ~100-400 for Gaussian data)
#define NJ    12     // 12*1024 + 256 = 12544

// Replicate jax f32 sample position: fl32((i+0.5f)*fl32(16/112)) - 0.5f.
// Double product + truncation = exact f32 round-to-nearest multiply, not fusable.
__device__ __forceinline__ float sample_pos(int i) {
    const double inv = (double)(16.0f / 112.0f);
    float prod = (float)(((double)i + 0.5) * inv);
    return prod - 0.5f;
}

struct BL { int i0, i1; float w; };

__device__ __forceinline__ BL bl_coeff(int i) {
    float s = sample_pos(i);
    s = fminf(fmaxf(s, 0.0f), 15.0f);   // clamp FIRST -> clamp groups bit-identical
    int i0 = (int)s;
    if (i0 > GRID - 2) i0 = GRID - 2;
    BL r;
    r.i0 = i0;
    r.i1 = i0 + 1;
    r.w  = s - (float)i0;               // exact (Sterbenz)
    return r;
}

// Orderable transform: ascending finite float <-> ascending unsigned.
__device__ __forceinline__ unsigned ordkey(float f) {
    unsigned u = __float_as_uint(f);
    return u ^ ((u & 0x80000000u) ? 0xFFFFFFFFu : 0x80000000u);
}

// tc[i] = {bitcast(i0), w}; av[yi*16+xi] = {amean[yi][xi], amean[yi+1][xi]}.
// One b64 read each -> 4 LDS ops/pixel (2 tc + 2 av) vs 8. Arithmetic is
// bit-identical to the verified kernel (same values, same op order).
__device__ __forceinline__ unsigned bilin_key(const float2* av, const float2* tc,
                                              int idx) {
    int y = idx / IMG, x = idx - y * IMG;
    float2 ty = tc[y], tx = tc[x];
    int yi0 = __float_as_int(ty.x), xi0 = __float_as_int(tx.x);
    float wy = ty.y, wx = tx.y;
    float2 a0 = av[yi0 * GRID + xi0];
    float2 a1 = av[yi0 * GRID + xi0 + 1];
    float top = (1.0f - wx) * a0.x + wx * a1.x;
    float bot = (1.0f - wx) * a0.y + wx * a1.y;
    float v   = (1.0f - wy) * top + wy * bot;
    return ordkey(v);
}

// Fused: each block (g, b) redundantly computes batch b's top-64 (phase 1,
// identical to the verified two-kernel topk), then computes features for its
// own 4 pixels (phase 2, register-tiled GEMV).
extern "C" __global__ void __launch_bounds__(1024)
fused_kernel(const float* __restrict__ attn, const float* __restrict__ lf,
             const float* __restrict__ pt, const float* __restrict__ cw,
             const float* __restrict__ cb, const float* __restrict__ bg,
             const float* __restrict__ bb, const float* __restrict__ bm,
             const float* __restrict__ bvr, float* __restrict__ out) {
    __shared__ float    amean[GRID * GRID];
    __shared__ float2   av[240];         // yi0 in 0..14
    __shared__ float2   tc[IMG];
    __shared__ unsigned hist[8][NBIN];   // 64 KB, per-wave-pair copies
    __shared__ unsigned wtot[16];
    __shared__ unsigned s_T;
    __shared__ int      s_nc;
    __shared__ unsigned candk[CAP];
    __shared__ int      candi[CAP];
    __shared__ int      topidx[KTOP];
    __shared__ __align__(16) float comb[4][CIN];   // 8 KB
    __shared__ __align__(16) float vmat[4][COUT];
    __shared__ float snrm[4];

    const int g = blockIdx.x;    // pixel group: 4 topk pixels
    const int b = blockIdx.y;    // batch
    const int t = threadIdx.x;
    const int lane = t & 63;
    const int wv = t >> 6;       // 0..15
    const int hc = wv >> 1;      // 8 histogram copies

    // ---------------- phase 1: top-64 for batch b ----------------
    if (t < 256) {
        float s = 0.0f;
        for (int h = 0; h < NHEADS; ++h)
            s += attn[(((size_t)b * NHEADS + h) << 8) + t];
        amean[t] = s * (1.0f / 6.0f);
    } else if (t < 256 + IMG) {
        int i = t - 256;
        BL c = bl_coeff(i);
        tc[i] = make_float2(__int_as_float(c.i0), c.w);
    }
    for (int i = t; i < 8 * NBIN; i += 1024) ((unsigned*)hist)[i] = 0;
    if (t == 0) s_nc = 0;
    __syncthreads();
    if (t < 240) av[t] = make_float2(amean[t], amean[t + 16]);
    __syncthreads();

    // 12.25 resized values per thread (bit-identical arithmetic). Lane->pixel
    // rotation decorrelates histogram bins within a wave.
    const int pt_ = (((t & 63) << 4) | (t >> 6)) & 1023;   // bijection on 0..1023
    unsigned lk[NJ];
    unsigned tailk = 0;
#pragma unroll
    for (int j = 0; j < NJ; ++j) {
        unsigned key = bilin_key(av, tc, j * 1024 + pt_);
        lk[j] = key;
        atomicAdd(&hist[hc][key >> 21], 1u);
    }
    if (t < 256) {
        tailk = bilin_key(av, tc, NJ * 1024 + t);
        atomicAdd(&hist[hc][tailk >> 21], 1u);
    }
    __syncthreads();

    // block-wide suffix scan over 2048 bins (2 bins per thread): find bin T
    // such that count(bin >= T) >= 64 > count(bin >= T+1)
    unsigned c0 = 0, c1 = 0;
    {
        const int bin0 = t * 2;
#pragma unroll
        for (int k = 0; k < 8; ++k) { c0 += hist[k][bin0]; c1 += hist[k][bin0 + 1]; }
    }
    const unsigned tot = c0 + c1;
    unsigned v = tot;   // inclusive suffix within wave
    for (int off = 1; off < 64; off <<= 1) {
        unsigned o = __shfl_down(v, off);
        if (lane + off < 64) v += o;
    }
    if (lane == 0) wtot[wv] = v;
    __syncthreads();
    unsigned add = 0;
    for (int w = wv + 1; w < 16; ++w) add += wtot[w];
    const unsigned S = v + add;          // count in bins >= t*2
    const unsigned above = S - tot;      // count in bins >= t*2+2
    const unsigned cum1 = above + c1;    // bins >= t*2+1
    if (cum1 >= KTOP && above < KTOP) s_T = (unsigned)(t * 2 + 1);
    const unsigned cum0 = cum1 + c0;     // bins >= t*2
    if (cum0 >= KTOP && cum1 < KTOP) s_T = (unsigned)(t * 2);
    __syncthreads();
    const unsigned T = s_T;

    // collect all candidates with bin >= T
#pragma unroll
    for (int j = 0; j < NJ; ++j) {
        unsigned key = lk[j];
        if ((key >> 21) >= T) {
            int sl = atomicAdd(&s_nc, 1);
            if (sl < CAP) { candk[sl] = key; candi[sl] = j * 1024 + pt_; }
        }
    }
    if (t < 256 && (tailk >> 21) >= T) {
        int sl = atomicAdd(&s_nc, 1);
        if (sl < CAP) { candk[sl] = tailk; candi[sl] = NJ * 1024 + t; }
    }
    __syncthreads();

    // exact stable rank select, 4 threads per candidate (rank depends only on
    // the candidate SET, so insertion order is irrelevant):
    // total order (key desc, idx asc) == jax.lax.top_k
    const int n = s_nc < CAP ? s_nc : CAP;
    const int q = t & 3;
    for (int c = t >> 2; c < n; c += 256) {
        unsigned myk = candk[c]; int myi = candi[c];
        int r = 0;
        for (int j2 = q; j2 < n; j2 += 4) {
            unsigned k2 = candk[j2];
            r += (k2 > myk) || (k2 == myk && candi[j2] < myi);
        }
        r += __shfl_xor(r, 1);
        r += __shfl_xor(r, 2);
        if (q == 0 && r < KTOP) topidx[r] = myi;
    }
    __syncthreads();

    // ---------------- phase 2: features for this block's 4 pixels ----------------
    int pidx[4];
#pragma unroll
    for (int i = 0; i < 4; ++i) pidx[i] = topidx[g * 4 + i];

    int   yi0[4], xi0[4];
    float wyv[4], wxv[4];
#pragma unroll
    for (int px = 0; px < 4; ++px) {
        const int idx = pidx[px];
        const int y = idx / IMG, x = idx - y * IMG;
        BL by = bl_coeff(y), bx = bl_coeff(x);
        yi0[px] = by.i0; xi0[px] = bx.i0; wyv[px] = by.w; wxv[px] = bx.w;
    }
    // stage comb[4][512]: thread -> (c = t&511, px = (t>>9)*2 + pp)
    {
        const int c = t & 511;
        const int ph = t >> 9;
        const float* ptb = pt + (size_t)b * 256 * DP;
#pragma unroll
        for (int pp = 0; pp < 2; ++pp) {
            const int px = ph * 2 + pp;
            float val;
            if (c < DP) {
                const int base = yi0[px] * GRID + xi0[px];
                float p00 = ptb[(size_t)base * DP + c];
                float p01 = ptb[(size_t)(base + 1) * DP + c];
                float p10 = ptb[(size_t)(base + GRID) * DP + c];
                float p11 = ptb[(size_t)(base + GRID + 1) * DP + c];
                float top = (1.0f - wxv[px]) * p00 + wxv[px] * p01;
                float bot = (1.0f - wxv[px]) * p10 + wxv[px] * p11;
                val = (1.0f - wyv[px]) * top + wyv[px] * bot;
            } else {
                val = lf[((size_t)b * CF + (c - DP)) * HW + pidx[px]];
            }
            comb[px][c] = val;
        }
    }
    __syncthreads();

    // Register-tiled GEMV (threads 0..511): thread (c4 = t>>4, l = t&15)
    // owns a 4px x 4ch accumulator tile over K-slice {i*64 + l*4}.
    // Per iter: 4 comb b128 (reused over 4 ch) + 4 coalesced w float4
    // (16 lanes x 16B = 256B contiguous per ch, each element read once).
    // Block LDS: 256 wave-b128 (was 1024). K-reduce: 4 shfl_xor steps.
    if (t < 512) {
        const int c4 = t >> 4, l = t & 15;
        float acc[4][4];   // [px][j]
#pragma unroll
        for (int p = 0; p < 4; ++p)
#pragma unroll
            for (int j = 0; j < 4; ++j) acc[p][j] = 0.0f;

        const float* wbase = cw + (size_t)c4 * 4 * CIN + l * 4;
#pragma unroll
        for (int i = 0; i < 8; ++i) {
            const int k = i * 64 + l * 4;
            float4 w0 = *(const float4*)(wbase + i * 64);
            float4 w1 = *(const float4*)(wbase + CIN + i * 64);
            float4 w2 = *(const float4*)(wbase + 2 * CIN + i * 64);
            float4 w3 = *(const float4*)(wbase + 3 * CIN + i * 64);
            float4 q0 = *(const float4*)(&comb[0][k]);
            float4 q1 = *(const float4*)(&comb[1][k]);
            float4 q2 = *(const float4*)(&comb[2][k]);
            float4 q3 = *(const float4*)(&comb[3][k]);
#define DOT4(W, C) ((W).x * (C).x + (W).y * (C).y + (W).z * (C).z + (W).w * (C).w)
            acc[0][0] += DOT4(w0, q0); acc[0][1] += DOT4(w1, q0);
            acc[0][2] += DOT4(w2, q0); acc[0][3] += DOT4(w3, q0);
            acc[1][0] += DOT4(w0, q1); acc[1][1] += DOT4(w1, q1);
            acc[1][2] += DOT4(w2, q1); acc[1][3] += DOT4(w3, q1);
            acc[2][0] += DOT4(w0, q2); acc[2][1] += DOT4(w1, q2);
            acc[2][2] += DOT4(w2, q2); acc[2][3] += DOT4(w3, q2);
            acc[3][0] += DOT4(w0, q3); acc[3][1] += DOT4(w1, q3);
            acc[3][2] += DOT4(w2, q3); acc[3][3] += DOT4(w3, q3);
#undef DOT4
        }
        // reduce K-split across the 16-lane group (in-wave shuffles)
#pragma unroll
        for (int p = 0; p < 4; ++p)
#pragma unroll
            for (int j = 0; j < 4; ++j) {
                acc[p][j] += __shfl_xor(acc[p][j], 1);
                acc[p][j] += __shfl_xor(acc[p][j], 2);
                acc[p][j] += __shfl_xor(acc[p][j], 4);
                acc[p][j] += __shfl_xor(acc[p][j], 8);
            }
        if (l == 0) {
#pragma unroll
            for (int j = 0; j < 4; ++j) {
                const int ch = c4 * 4 + j;
                float scale = bg[ch] / sqrtf(bvr[ch] + 1e-5f);
                float shift = bb[ch] - bm[ch] * scale;
                float base  = cb[ch];
#pragma unroll
                for (int p = 0; p < 4; ++p)
                    vmat[p][ch] = fmaxf((base + acc[p][j]) * scale + shift, 0.0f);
            }
        }
    }
    __syncthreads();

    // L2 norm per pixel (waves 0-3, one pixel each)
    if (wv < 4) {
        float x0 = vmat[wv][lane], x1 = vmat[wv][lane + 64];
        float ss = x0 * x0 + x1 * x1;
        for (int off = 32; off > 0; off >>= 1) ss += __shfl_xor(ss, off);
        if (lane == 0) snrm[wv] = sqrtf(ss);
    }
    __syncthreads();

    if (t < 512) {
        const int px = t & 3, c2 = t >> 2;
        out[((size_t)(b * COUT + c2)) * KTOP + g * 4 + px] =
            vmat[px][c2] / fmaxf(snrm[px], 1e-12f);
    }
}

extern "C" void kernel_launch(void* const* d_in, const int* in_sizes, int n_in,
                              void* d_out, int out_size, void* d_ws, size_t ws_size,
                              hipStream_t stream) {
    const float* lf   = (const float*)d_in[0];
    const float* pt   = (const float*)d_in[1];
    const float* attn = (const float*)d_in[2];
    const float* cw   = (const float*)d_in[3];
    const float* cb   = (const float*)d_in[4];
    const float* bg   = (const float*)d_in[5];
    const float* bb   = (const float*)d_in[6];
    const float* bm   = (const float*)d_in[7];
    const float* bvr  = (const float*)d_in[8];
    float* out = (float*)d_out;
    const int B = in_sizes[0] / (CF * HW);

    hipLaunchKernelGGL(fused_kernel, dim3(KTOP / 4, B), dim3(1024), 0, stream,
                       attn, lf, pt, cw, cb, bg, bb, bm, bvr, out);
}

// Round 8
// 21.432 us; speedup vs baseline: 1.1688x; 1.1688x over previous
//
#include <hip/hip_runtime.h>
#include <math.h>

#define IMG   112
#define HW    12544
#define GRID  16
#define DP    384
#define CF    128
#define CIN   512
#define COUT  128
#define KTOP  64
#define NHEADS 6
#define NBIN  2048   // 11-bit bins of the orderable key
#define CAP   2048   // candidate capacity (expected ~100-400 for Gaussian data)
#define NJ    12     // 12*1024 + 256 = 12544

// Replicate jax f32 sample position: fl32((i+0.5f)*fl32(16/112)) - 0.5f.
// Double product + truncation = exact f32 round-to-nearest multiply, not fusable.
__device__ __forceinline__ float sample_pos(int i) {
    const double inv = (double)(16.0f / 112.0f);
    float prod = (float)(((double)i + 0.5) * inv);
    return prod - 0.5f;
}

struct BL { int i0, i1; float w; };

__device__ __forceinline__ BL bl_coeff(int i) {
    float s = sample_pos(i);
    s = fminf(fmaxf(s, 0.0f), 15.0f);   // clamp FIRST -> clamp groups bit-identical
    int i0 = (int)s;
    if (i0 > GRID - 2) i0 = GRID - 2;
    BL r;
    r.i0 = i0;
    r.i1 = i0 + 1;
    r.w  = s - (float)i0;               // exact (Sterbenz)
    return r;
}

// Orderable transform: ascending finite float <-> ascending unsigned.
__device__ __forceinline__ unsigned ordkey(float f) {
    unsigned u = __float_as_uint(f);
    return u ^ ((u & 0x80000000u) ? 0xFFFFFFFFu : 0x80000000u);
}

// Fused: each block (g, b) redundantly computes batch b's top-64 (phase 1),
// then computes features for its own 4 pixels (phase 2).
// Phase 1 uses the separability of bilinear resize: rp[yi][x] holds the
// reference's (top, bot) row-interpolations verbatim, so the per-pixel value
// v = (1-wy)*rp.x + wy*rp.y is bit-identical to the verified kernels.
extern "C" __global__ void __launch_bounds__(1024)
fused_kernel(const float* __restrict__ attn, const float* __restrict__ lf,
             const float* __restrict__ pt, const float* __restrict__ cw,
             const float* __restrict__ cb, const float* __restrict__ bg,
             const float* __restrict__ bb, const float* __restrict__ bm,
             const float* __restrict__ bvr, float* __restrict__ out) {
    __shared__ __align__(16) float    amean[GRID * GRID];
    __shared__ __align__(16) float2   tc[IMG];
    __shared__ __align__(16) float2   rp[15 * 128];   // [yi][x], x padded to 128
    __shared__ __align__(16) unsigned hist[8][NBIN];  // 64 KB, per-wave-pair copies
    __shared__ unsigned wtot[16];
    __shared__ unsigned s_T;
    __shared__ int      s_nc;
    __shared__ __align__(16) unsigned long long candp[CAP];
    __shared__ int      topidx[KTOP];
    __shared__ __align__(16) float comb[4][CIN];   // 8 KB
    __shared__ __align__(16) float vmat[4][COUT];
    __shared__ float snrm[4];

    const int g = blockIdx.x;    // pixel group: 4 topk pixels
    const int b = blockIdx.y;    // batch
    const int t = threadIdx.x;
    const int lane = t & 63;
    const int wv = t >> 6;       // 0..15
    const int hc = wv >> 1;      // 8 histogram copies

    // ---------------- phase 1: top-64 for batch b ----------------
    if (t < 256) {
        float s = 0.0f;
        for (int h = 0; h < NHEADS; ++h)
            s += attn[(((size_t)b * NHEADS + h) << 8) + t];
        amean[t] = s * (1.0f / 6.0f);
    } else if (t < 256 + IMG) {
        int i = t - 256;
        BL c = bl_coeff(i);
        tc[i] = make_float2(__int_as_float(c.i0), c.w);
    }
    // zero 8 histogram copies with b128 writes (4 per thread)
    {
        uint4* h4 = (uint4*)hist;
        const uint4 z = make_uint4(0, 0, 0, 0);
#pragma unroll
        for (int i = 0; i < 4; ++i) h4[t + i * 1024] = z;
    }
    if (t == 0) s_nc = 0;
    __syncthreads();

    // build rp[yi][x] = {top, bot} row-interpolations (reference expressions)
    for (int e = t; e < 15 * 128; e += 1024) {
        const int yi = e >> 7, x = e & 127;
        if (x < IMG) {
            float2 tx = tc[x];
            const int xi0 = __float_as_int(tx.x);
            const float wx = tx.y;
            const float* r0 = &amean[yi * GRID];
            float top = (1.0f - wx) * r0[xi0] + wx * r0[xi0 + 1];
            float bot = (1.0f - wx) * r0[GRID + xi0] + wx * r0[GRID + xi0 + 1];
            rp[e] = make_float2(top, bot);
        }
    }
    __syncthreads();

    // 12.25 resized values per thread. Lane->pixel stride 85 (odd) gives full
    // bank spread on rp reads and decorrelates histogram bins within a wave.
    const int pt_ = (t * 85) & 1023;   // bijection on 0..1023
    unsigned lk[NJ];
    unsigned tailk = 0;
#pragma unroll
    for (int j = 0; j < NJ; ++j) {
        const int idx = j * 1024 + pt_;
        const int y = idx / IMG, x = idx - y * IMG;
        float2 ty = tc[y];
        const int yi0 = __float_as_int(ty.x);
        const float wy = ty.y;
        float2 pr = rp[yi0 * 128 + x];
        float v = (1.0f - wy) * pr.x + wy * pr.y;
        unsigned key = ordkey(v);
        lk[j] = key;
        atomicAdd(&hist[hc][key >> 21], 1u);
    }
    if (t < 256) {
        const int idx = NJ * 1024 + t;
        const int y = idx / IMG, x = idx - y * IMG;
        float2 ty = tc[y];
        float2 pr = rp[__float_as_int(ty.x) * 128 + x];
        float v = (1.0f - ty.y) * pr.x + ty.y * pr.y;
        tailk = ordkey(v);
        atomicAdd(&hist[hc][tailk >> 21], 1u);
    }
    __syncthreads();

    // block-wide suffix scan over 2048 bins (2 bins per thread): find bin T
    // such that count(bin >= T) >= 64 > count(bin >= T+1)
    unsigned c0 = 0, c1 = 0;
#pragma unroll
    for (int k = 0; k < 8; ++k) {
        uint2 h2 = ((const uint2*)&hist[k][0])[t];
        c0 += h2.x; c1 += h2.y;
    }
    const unsigned tot = c0 + c1;
    unsigned v = tot;   // inclusive suffix within wave
    for (int off = 1; off < 64; off <<= 1) {
        unsigned o = __shfl_down(v, off);
        if (lane + off < 64) v += o;
    }
    if (lane == 0) wtot[wv] = v;
    __syncthreads();
    unsigned add = 0;
    for (int w = wv + 1; w < 16; ++w) add += wtot[w];
    const unsigned S = v + add;          // count in bins >= t*2
    const unsigned above = S - tot;      // count in bins >= t*2+2
    const unsigned cum1 = above + c1;    // bins >= t*2+1
    if (cum1 >= KTOP && above < KTOP) s_T = (unsigned)(t * 2 + 1);
    const unsigned cum0 = cum1 + c0;     // bins >= t*2
    if (cum0 >= KTOP && cum1 < KTOP) s_T = (unsigned)(t * 2);
    __syncthreads();
    const unsigned T = s_T;

    // collect candidates with bin >= T, packed (key desc, idx asc) == desc u64:
    // P = (key << 14) | (16383 - idx)
#pragma unroll
    for (int j = 0; j < NJ; ++j) {
        unsigned key = lk[j];
        if ((key >> 21) >= T) {
            int sl = atomicAdd(&s_nc, 1);
            if (sl < CAP)
                candp[sl] = ((unsigned long long)key << 14)
                          | (unsigned)(16383 - (j * 1024 + pt_));
        }
    }
    if (t < 256 && (tailk >> 21) >= T) {
        int sl = atomicAdd(&s_nc, 1);
        if (sl < CAP)
            candp[sl] = ((unsigned long long)tailk << 14)
                      | (unsigned)(16383 - (NJ * 1024 + t));
    }
    __syncthreads();

    // exact stable rank select, 4 threads per candidate (rank depends only on
    // the candidate SET): rank = #{P2 > P}; order == jax.lax.top_k
    const int n = s_nc < CAP ? s_nc : CAP;
    const int q = t & 3;
    for (int c = t >> 2; c < n; c += 256) {
        const unsigned long long myp = candp[c];
        int r = 0;
        for (int j2 = q; j2 < n; j2 += 4)
            r += (candp[j2] > myp);
        r += __shfl_xor(r, 1);
        r += __shfl_xor(r, 2);
        if (q == 0 && r < KTOP)
            topidx[r] = 16383 - (int)(myp & 16383u);
    }
    __syncthreads();

    // ---------------- phase 2: features for this block's 4 pixels ----------------
    int pidx[4];
#pragma unroll
    for (int i = 0; i < 4; ++i) pidx[i] = topidx[g * 4 + i];

    int   yi0a[4], xi0a[4];
    float wyv[4], wxv[4];
#pragma unroll
    for (int px = 0; px < 4; ++px) {
        const int idx = pidx[px];
        const int y = idx / IMG, x = idx - y * IMG;
        BL by = bl_coeff(y), bx = bl_coeff(x);
        yi0a[px] = by.i0; xi0a[px] = bx.i0; wyv[px] = by.w; wxv[px] = bx.w;
    }
    // stage comb[4][512]: thread -> (c = t&511, px = (t>>9)*2 + pp)
    {
        const int c = t & 511;
        const int ph = t >> 9;
        const float* ptb = pt + (size_t)b * 256 * DP;
#pragma unroll
        for (int pp = 0; pp < 2; ++pp) {
            const int px = ph * 2 + pp;
            float val;
            if (c < DP) {
                const int base = yi0a[px] * GRID + xi0a[px];
                float p00 = ptb[(size_t)base * DP + c];
                float p01 = ptb[(size_t)(base + 1) * DP + c];
                float p10 = ptb[(size_t)(base + GRID) * DP + c];
                float p11 = ptb[(size_t)(base + GRID + 1) * DP + c];
                float top = (1.0f - wxv[px]) * p00 + wxv[px] * p01;
                float bot = (1.0f - wxv[px]) * p10 + wxv[px] * p11;
                val = (1.0f - wyv[px]) * top + wyv[px] * bot;
            } else {
                val = lf[((size_t)b * CF + (c - DP)) * HW + pidx[px]];
            }
            comb[px][c] = val;
        }
    }
    __syncthreads();

    // Register-tiled GEMV (threads 0..511): thread (c4 = t>>4, l = t&15)
    // owns a 4px x 4ch accumulator tile over K-slice {i*64 + l*4}.
    if (t < 512) {
        const int c4 = t >> 4, l = t & 15;
        float acc[4][4];   // [px][j]
#pragma unroll
        for (int p = 0; p < 4; ++p)
#pragma unroll
            for (int j = 0; j < 4; ++j) acc[p][j] = 0.0f;

        const float* wbase = cw + (size_t)c4 * 4 * CIN + l * 4;
#pragma unroll
        for (int i = 0; i < 8; ++i) {
            const int k = i * 64 + l * 4;
            float4 w0 = *(const float4*)(wbase + i * 64);
            float4 w1 = *(const float4*)(wbase + CIN + i * 64);
            float4 w2 = *(const float4*)(wbase + 2 * CIN + i * 64);
            float4 w3 = *(const float4*)(wbase + 3 * CIN + i * 64);
            float4 q0 = *(const float4*)(&comb[0][k]);
            float4 q1 = *(const float4*)(&comb[1][k]);
            float4 q2 = *(const float4*)(&comb[2][k]);
            float4 q3 = *(const float4*)(&comb[3][k]);
#define DOT4(W, C) ((W).x * (C).x + (W).y * (C).y + (W).z * (C).z + (W).w * (C).w)
            acc[0][0] += DOT4(w0, q0); acc[0][1] += DOT4(w1, q0);
            acc[0][2] += DOT4(w2, q0); acc[0][3] += DOT4(w3, q0);
            acc[1][0] += DOT4(w0, q1); acc[1][1] += DOT4(w1, q1);
            acc[1][2] += DOT4(w2, q1); acc[1][3] += DOT4(w3, q1);
            acc[2][0] += DOT4(w0, q2); acc[2][1] += DOT4(w1, q2);
            acc[2][2] += DOT4(w2, q2); acc[2][3] += DOT4(w3, q2);
            acc[3][0] += DOT4(w0, q3); acc[3][1] += DOT4(w1, q3);
            acc[3][2] += DOT4(w2, q3); acc[3][3] += DOT4(w3, q3);
#undef DOT4
        }
        // reduce K-split across the 16-lane group (in-wave shuffles)
#pragma unroll
        for (int p = 0; p < 4; ++p)
#pragma unroll
            for (int j = 0; j < 4; ++j) {
                acc[p][j] += __shfl_xor(acc[p][j], 1);
                acc[p][j] += __shfl_xor(acc[p][j], 2);
                acc[p][j] += __shfl_xor(acc[p][j], 4);
                acc[p][j] += __shfl_xor(acc[p][j], 8);
            }
        if (l == 0) {
#pragma unroll
            for (int j = 0; j < 4; ++j) {
                const int ch = c4 * 4 + j;
                float scale = bg[ch] / sqrtf(bvr[ch] + 1e-5f);
                float shift = bb[ch] - bm[ch] * scale;
                float base  = cb[ch];
#pragma unroll
                for (int p = 0; p < 4; ++p)
                    vmat[p][ch] = fmaxf((base + acc[p][j]) * scale + shift, 0.0f);
            }
        }
    }
    __syncthreads();

    // L2 norm per pixel (waves 0-3, one pixel each)
    if (wv < 4) {
        float x0 = vmat[wv][lane], x1 = vmat[wv][lane + 64];
        float ss = x0 * x0 + x1 * x1;
        for (int off = 32; off > 0; off >>= 1) ss += __shfl_xor(ss, off);
        if (lane == 0) snrm[wv] = sqrtf(ss);
    }
    __syncthreads();

    if (t < 512) {
        const int px = t & 3, c2 = t >> 2;
        out[((size_t)(b * COUT + c2)) * KTOP + g * 4 + px] =
            vmat[px][c2] / fmaxf(snrm[px], 1e-12f);
    }
}

extern "C" void kernel_launch(void* const* d_in, const int* in_sizes, int n_in,
                              void* d_out, int out_size, void* d_ws, size_t ws_size,
                              hipStream_t stream) {
    const float* lf   = (const float*)d_in[0];
    const float* pt   = (const float*)d_in[1];
    const float* attn = (const float*)d_in[2];
    const float* cw   = (const float*)d_in[3];
    const float* cb   = (const float*)d_in[4];
    const float* bg   = (const float*)d_in[5];
    const float* bb   = (const float*)d_in[6];
    const float* bm   = (const float*)d_in[7];
    const float* bvr  = (const float*)d_in[8];
    float* out = (float*)d_out;
    const int B = in_sizes[0] / (CF * HW);

    hipLaunchKernelGGL(fused_kernel, dim3(KTOP / 4, B), dim3(1024), 0, stream,
                       attn, lf, pt, cw, cb, bg, bb, bm, bvr, out);
}

// Round 9
// 19.418 us; speedup vs baseline: 1.2900x; 1.1037x over previous
//
#include <hip/hip_runtime.h>
#include <math.h>

#define IMG   112
#define HW    12544
#define GRID  16
#define DP    384
#define CF    128
#define CIN   512
#define COUT  128
#define KTOP  64
#define NHEADS 6
#define NBIN  8192   // 13-bit bins of the orderable key
#define CAP   2048   // candidate capacity (expected ~100 for Gaussian data)
#define NJ    12     // 12*1024 + 256 = 12544

// Replicate jax f32 sample position: fl32((i+0.5f)*fl32(16/112)) - 0.5f.
// Double product + truncation = exact f32 round-to-nearest multiply, not fusable.
__device__ __forceinline__ float sample_pos(int i) {
    const double inv = (double)(16.0f / 112.0f);
    float prod = (float)(((double)i + 0.5) * inv);
    return prod - 0.5f;
}

struct BL { int i0, i1; float w; };

__device__ __forceinline__ BL bl_coeff(int i) {
    float s = sample_pos(i);
    s = fminf(fmaxf(s, 0.0f), 15.0f);   // clamp FIRST -> clamp groups bit-identical
    int i0 = (int)s;
    if (i0 > GRID - 2) i0 = GRID - 2;
    BL r;
    r.i0 = i0;
    r.i1 = i0 + 1;
    r.w  = s - (float)i0;               // exact (Sterbenz)
    return r;
}

// Orderable transform: ascending finite float <-> ascending unsigned.
__device__ __forceinline__ unsigned ordkey(float f) {
    unsigned u = __float_as_uint(f);
    return u ^ ((u & 0x80000000u) ? 0xFFFFFFFFu : 0x80000000u);
}

// Fused: each block (g, b) redundantly computes batch b's top-64 (phase 1),
// then computes features for its own 4 pixels (phase 2).
// Phase 1 uses the separability of bilinear resize: rp[yi][x] holds the
// reference's (top, bot) row-interpolations verbatim, so the per-pixel value
// v = (1-wy)*rp.x + wy*rp.y is bit-identical to the verified kernels.
// Histogram: 13-bit bins, two 16-bit counters packed per u32 word
// (max count per copy = 256 threads * 13 px = 3328 << 65536, no carry).
extern "C" __global__ void __launch_bounds__(1024)
fused_kernel(const float* __restrict__ attn, const float* __restrict__ lf,
             const float* __restrict__ pt, const float* __restrict__ cw,
             const float* __restrict__ cb, const float* __restrict__ bg,
             const float* __restrict__ bb, const float* __restrict__ bm,
             const float* __restrict__ bvr, float* __restrict__ out) {
    __shared__ __align__(16) float    amean[GRID * GRID];
    __shared__ __align__(16) float2   tc[IMG];
    __shared__ __align__(16) float2   rp[15 * 128];      // [yi][x], x padded to 128
    __shared__ __align__(16) unsigned hist[4][NBIN / 2]; // 64 KB, 4 copies, packed
    __shared__ unsigned wtot[16];
    __shared__ unsigned s_T;
    __shared__ int      s_nc;
    __shared__ __align__(16) unsigned long long candp[CAP];
    __shared__ int      topidx[KTOP];
    __shared__ __align__(16) float comb[4][CIN];   // 8 KB
    __shared__ __align__(16) float vmat[4][COUT];
    __shared__ float snrm[4];

    const int g = blockIdx.x;    // pixel group: 4 topk pixels
    const int b = blockIdx.y;    // batch
    const int t = threadIdx.x;
    const int lane = t & 63;
    const int wv = t >> 6;       // 0..15
    const int hc = wv >> 2;      // 4 histogram copies

    // ---------------- phase 1: top-64 for batch b ----------------
    if (t < 256) {
        float s = 0.0f;
        for (int h = 0; h < NHEADS; ++h)
            s += attn[(((size_t)b * NHEADS + h) << 8) + t];
        amean[t] = s * (1.0f / 6.0f);
    } else if (t < 256 + IMG) {
        int i = t - 256;
        BL c = bl_coeff(i);
        tc[i] = make_float2(__int_as_float(c.i0), c.w);
    }
    // zero 4 packed histogram copies with b128 writes (4 per thread)
    {
        uint4* h4 = (uint4*)hist;
        const uint4 z = make_uint4(0, 0, 0, 0);
#pragma unroll
        for (int i = 0; i < 4; ++i) h4[t + i * 1024] = z;
    }
    if (t == 0) s_nc = 0;
    __syncthreads();

    // build rp[yi][x] = {top, bot} row-interpolations (reference expressions)
    for (int e = t; e < 15 * 128; e += 1024) {
        const int yi = e >> 7, x = e & 127;
        if (x < IMG) {
            float2 tx = tc[x];
            const int xi0 = __float_as_int(tx.x);
            const float wx = tx.y;
            const float* r0 = &amean[yi * GRID];
            float top = (1.0f - wx) * r0[xi0] + wx * r0[xi0 + 1];
            float bot = (1.0f - wx) * r0[GRID + xi0] + wx * r0[GRID + xi0 + 1];
            rp[e] = make_float2(top, bot);
        }
    }
    __syncthreads();

    // 12.25 resized values per thread. Lane->pixel stride 85 (odd) gives full
    // bank spread on rp reads and decorrelates histogram bins within a wave.
    // (y,x) advanced incrementally: step 1024 = 9*112 + 16 (no per-pixel div).
    const int pt_ = (t * 85) & 1023;   // bijection on 0..1023
    unsigned lk[NJ];
    unsigned tailk = 0;
    {
        int y = pt_ / IMG, x = pt_ - (pt_ / IMG) * IMG;
#pragma unroll
        for (int j = 0; j < NJ; ++j) {
            float2 ty = tc[y];
            const int yi0 = __float_as_int(ty.x);
            const float wy = ty.y;
            float2 pr = rp[yi0 * 128 + x];
            float v = (1.0f - wy) * pr.x + wy * pr.y;
            unsigned key = ordkey(v);
            lk[j] = key;
            const unsigned bin = key >> 19;
            atomicAdd(&hist[hc][bin >> 1], 1u << ((bin & 1) << 4));
            x += 16; y += 9;
            if (x >= IMG) { x -= IMG; y += 1; }
        }
    }
    if (t < 256) {
        const int idx = NJ * 1024 + t;
        const int y = idx / IMG, x = idx - y * IMG;
        float2 ty = tc[y];
        float2 pr = rp[__float_as_int(ty.x) * 128 + x];
        float v = (1.0f - ty.y) * pr.x + ty.y * pr.y;
        tailk = ordkey(v);
        const unsigned bin = tailk >> 19;
        atomicAdd(&hist[hc][bin >> 1], 1u << ((bin & 1) << 4));
    }
    __syncthreads();

    // block-wide suffix scan over 8192 bins (8 bins = 4 words per thread):
    // find bin T with count(bin >= T) >= 64 > count(bin >= T+1)
    unsigned cnt[8] = {0, 0, 0, 0, 0, 0, 0, 0};
#pragma unroll
    for (int k = 0; k < 4; ++k) {
        uint4 h4 = ((const uint4*)&hist[k][0])[t];   // words 4t..4t+3
        cnt[0] += h4.x & 0xFFFFu; cnt[1] += h4.x >> 16;
        cnt[2] += h4.y & 0xFFFFu; cnt[3] += h4.y >> 16;
        cnt[4] += h4.z & 0xFFFFu; cnt[5] += h4.z >> 16;
        cnt[6] += h4.w & 0xFFFFu; cnt[7] += h4.w >> 16;
    }
    unsigned tot = 0;
#pragma unroll
    for (int i = 0; i < 8; ++i) tot += cnt[i];
    unsigned v = tot;   // inclusive suffix within wave
    for (int off = 1; off < 64; off <<= 1) {
        unsigned o = __shfl_down(v, off);
        if (lane + off < 64) v += o;
    }
    if (lane == 0) wtot[wv] = v;
    __syncthreads();
    unsigned add = 0;
    for (int w = wv + 1; w < 16; ++w) add += wtot[w];
    const unsigned S = v + add;          // count in bins >= t*8
    unsigned suf = S - tot;              // count in bins >= (t+1)*8
#pragma unroll
    for (int i = 7; i >= 0; --i) {       // exactly one (t,i) brackets KTOP
        unsigned cum = suf + cnt[i];
        if (cum >= KTOP && suf < KTOP) s_T = (unsigned)(t * 8 + i);
        suf = cum;
    }
    __syncthreads();
    const unsigned T = s_T;

    // collect candidates with bin >= T, packed (key desc, idx asc) == desc u64:
    // P = (key << 14) | (16383 - idx)
#pragma unroll
    for (int j = 0; j < NJ; ++j) {
        unsigned key = lk[j];
        if ((key >> 19) >= T) {
            int sl = atomicAdd(&s_nc, 1);
            if (sl < CAP)
                candp[sl] = ((unsigned long long)key << 14)
                          | (unsigned)(16383 - (j * 1024 + pt_));
        }
    }
    if (t < 256 && (tailk >> 19) >= T) {
        int sl = atomicAdd(&s_nc, 1);
        if (sl < CAP)
            candp[sl] = ((unsigned long long)tailk << 14)
                      | (unsigned)(16383 - (NJ * 1024 + t));
    }
    __syncthreads();

    // exact stable rank select, 4 threads per candidate (rank depends only on
    // the candidate SET): rank = #{P2 > P}; order == jax.lax.top_k
    const int n = s_nc < CAP ? s_nc : CAP;
    const int q = t & 3;
    for (int c = t >> 2; c < n; c += 256) {
        const unsigned long long myp = candp[c];
        int r = 0;
        for (int j2 = q; j2 < n; j2 += 4)
            r += (candp[j2] > myp);
        r += __shfl_xor(r, 1);
        r += __shfl_xor(r, 2);
        if (q == 0 && r < KTOP)
            topidx[r] = 16383 - (int)(myp & 16383u);
    }
    __syncthreads();

    // ---------------- phase 2: features for this block's 4 pixels ----------------
    int pidx[4];
#pragma unroll
    for (int i = 0; i < 4; ++i) pidx[i] = topidx[g * 4 + i];

    int   yi0a[4], xi0a[4];
    float wyv[4], wxv[4];
#pragma unroll
    for (int px = 0; px < 4; ++px) {
        const int idx = pidx[px];
        const int y = idx / IMG, x = idx - y * IMG;
        BL by = bl_coeff(y), bx = bl_coeff(x);
        yi0a[px] = by.i0; xi0a[px] = bx.i0; wyv[px] = by.w; wxv[px] = bx.w;
    }
    // stage comb[4][512]: thread -> (c = t&511, px = (t>>9)*2 + pp)
    {
        const int c = t & 511;
        const int ph = t >> 9;
        const float* ptb = pt + (size_t)b * 256 * DP;
#pragma unroll
        for (int pp = 0; pp < 2; ++pp) {
            const int px = ph * 2 + pp;
            float val;
            if (c < DP) {
                const int base = yi0a[px] * GRID + xi0a[px];
                float p00 = ptb[(size_t)base * DP + c];
                float p01 = ptb[(size_t)(base + 1) * DP + c];
                float p10 = ptb[(size_t)(base + GRID) * DP + c];
                float p11 = ptb[(size_t)(base + GRID + 1) * DP + c];
                float top = (1.0f - wxv[px]) * p00 + wxv[px] * p01;
                float bot = (1.0f - wxv[px]) * p10 + wxv[px] * p11;
                val = (1.0f - wyv[px]) * top + wyv[px] * bot;
            } else {
                val = lf[((size_t)b * CF + (c - DP)) * HW + pidx[px]];
            }
            comb[px][c] = val;
        }
    }
    __syncthreads();

    // Register-tiled GEMV (threads 0..511): thread (c4 = t>>4, l = t&15)
    // owns a 4px x 4ch accumulator tile over K-slice {i*64 + l*4}.
    if (t < 512) {
        const int c4 = t >> 4, l = t & 15;
        float acc[4][4];   // [px][j]
#pragma unroll
        for (int p = 0; p < 4; ++p)
#pragma unroll
            for (int j = 0; j < 4; ++j) acc[p][j] = 0.0f;

        const float* wbase = cw + (size_t)c4 * 4 * CIN + l * 4;
#pragma unroll
        for (int i = 0; i < 8; ++i) {
            const int k = i * 64 + l * 4;
            float4 w0 = *(const float4*)(wbase + i * 64);
            float4 w1 = *(const float4*)(wbase + CIN + i * 64);
            float4 w2 = *(const float4*)(wbase + 2 * CIN + i * 64);
            float4 w3 = *(const float4*)(wbase + 3 * CIN + i * 64);
            float4 q0 = *(const float4*)(&comb[0][k]);
            float4 q1 = *(const float4*)(&comb[1][k]);
            float4 q2 = *(const float4*)(&comb[2][k]);
            float4 q3 = *(const float4*)(&comb[3][k]);
#define DOT4(W, C) ((W).x * (C).x + (W).y * (C).y + (W).z * (C).z + (W).w * (C).w)
            acc[0][0] += DOT4(w0, q0); acc[0][1] += DOT4(w1, q0);
            acc[0][2] += DOT4(w2, q0); acc[0][3] += DOT4(w3, q0);
            acc[1][0] += DOT4(w0, q1); acc[1][1] += DOT4(w1, q1);
            acc[1][2] += DOT4(w2, q1); acc[1][3] += DOT4(w3, q1);
            acc[2][0] += DOT4(w0, q2); acc[2][1] += DOT4(w1, q2);
            acc[2][2] += DOT4(w2, q2); acc[2][3] += DOT4(w3, q2);
            acc[3][0] += DOT4(w0, q3); acc[3][1] += DOT4(w1, q3);
            acc[3][2] += DOT4(w2, q3); acc[3][3] += DOT4(w3, q3);
#undef DOT4
        }
        // reduce K-split across the 16-lane group (in-wave shuffles)
#pragma unroll
        for (int p = 0; p < 4; ++p)
#pragma unroll
            for (int j = 0; j < 4; ++j) {
                acc[p][j] += __shfl_xor(acc[p][j], 1);
                acc[p][j] += __shfl_xor(acc[p][j], 2);
                acc[p][j] += __shfl_xor(acc[p][j], 4);
                acc[p][j] += __shfl_xor(acc[p][j], 8);
            }
        if (l == 0) {
#pragma unroll
            for (int j = 0; j < 4; ++j) {
                const int ch = c4 * 4 + j;
                float scale = bg[ch] / sqrtf(bvr[ch] + 1e-5f);
                float shift = bb[ch] - bm[ch] * scale;
                float base  = cb[ch];
#pragma unroll
                for (int p = 0; p < 4; ++p)
                    vmat[p][ch] = fmaxf((base + acc[p][j]) * scale + shift, 0.0f);
            }
        }
    }
    __syncthreads();

    // L2 norm per pixel (waves 0-3, one pixel each)
    if (wv < 4) {
        float x0 = vmat[wv][lane], x1 = vmat[wv][lane + 64];
        float ss = x0 * x0 + x1 * x1;
        for (int off = 32; off > 0; off >>= 1) ss += __shfl_xor(ss, off);
        if (lane == 0) snrm[wv] = sqrtf(ss);
    }
    __syncthreads();

    if (t < 512) {
        const int px = t & 3, c2 = t >> 2;
        out[((size_t)(b * COUT + c2)) * KTOP + g * 4 + px] =
            vmat[px][c2] / fmaxf(snrm[px], 1e-12f);
    }
}

extern "C" void kernel_launch(void* const* d_in, const int* in_sizes, int n_in,
                              void* d_out, int out_size, void* d_ws, size_t ws_size,
                              hipStream_t stream) {
    const float* lf   = (const float*)d_in[0];
    const float* pt   = (const float*)d_in[1];
    const float* attn = (const float*)d_in[2];
    const float* cw   = (const float*)d_in[3];
    const float* cb   = (const float*)d_in[4];
    const float* bg   = (const float*)d_in[5];
    const float* bb   = (const float*)d_in[6];
    const float* bm   = (const float*)d_in[7];
    const float* bvr  = (const float*)d_in[8];
    float* out = (float*)d_out;
    const int B = in_sizes[0] / (CF * HW);

    hipLaunchKernelGGL(fused_kernel, dim3(KTOP / 4, B), dim3(1024), 0, stream,
                       attn, lf, pt, cw, cb, bg, bb, bm, bvr, out);
}